// Round 5
// baseline (1465.618 us; speedup 1.0000x reference)
//
#include <hip/hip_runtime.h>
#include <math.h>

#define N_NODES 16384
#define N_EDGES 524288
#define D_FEAT  128
#define BATCH   4
#define NPTS    4096   // points per cloud
#define KSEL    2048   // selected per cloud
#define MSEL    (BATCH*KSEL)  // 8192
#define CAP     80     // per-sampled-node bucket capacity; deg~Poisson(32),
                       // P(deg>=80) ~ 4e-13/node -> safe; clamped anyway

#define X16(F) F(0) F(1) F(2) F(3) F(4) F(5) F(6) F(7) \
               F(8) F(9) F(10) F(11) F(12) F(13) F(14) F(15)

// ---------------------------------------------------------------------------
// FPS: R5 change — winner-carried coordinates. R4's loop had two serial
// post-barrier LDS round trips (pwv keys ~120cy -> tree -> query coords
// ~120cy). Now each lane speculatively reads its OWN candidate's coords
// (bank-conflict-free: addr = J*256+tid -> bank = tid&31) overlapping the
// DPP chain; v_readlane(63) broadcasts the wave max; the unique winner lane
// writes {key,x,y,z} to its slot; post-barrier a single concurrent read of
// 4x(key,xyz) + in-register tree/select yields cur AND the next query.
// Selection arithmetic, packing, tie-break, parity slots: unchanged.
// Regression log (do not reintroduce without counter evidence):
//   512thr/2-waves-per-SIMD +127us (R2: barrier-lockstep kills wave overlap);
//   LDS atomicMax(u64) reduce +150us (R3: RMW on pre-barrier lgkmcnt path);
//   pk-asm packed math +100us; tournament-tree argmax +20-60us; two-phase
//   f32/u32 reduce +160us; float4-interleaved query +worse; fusing deg
//   blocks into this dispatch +60us AND races on inv.
// inv is initialized by hipMemsetAsync(0xFF) BEFORE this kernel launches.
// ---------------------------------------------------------------------------

__device__ __forceinline__ unsigned long long dpp_max_step(unsigned long long p,
                                                           unsigned int slo,
                                                           unsigned int shi)
{
    unsigned long long s = (((unsigned long long)shi) << 32) | slo;
    return (s > p) ? s : p;
}

struct __align__(16) WSlot {
    unsigned long long key;
    float x, y, z;
    float pad;
};

__launch_bounds__(256, 1)
__global__ void fps_kernel(const float* __restrict__ pos,
                           int* __restrict__ fp_int,
                           int* __restrict__ inv,
                           float* __restrict__ out_subx,
                           float* __restrict__ out_fp)
{
    __shared__ float sx[NPTS];
    __shared__ float sy[NPTS];
    __shared__ float sz[NPTS];
    __shared__ int   sel[KSEL];
    __shared__ WSlot wsl[2][4];   // even/odd parity slots, one per wave

    const int b   = blockIdx.x;
    const int tid = threadIdx.x;

    const float* gp = pos + (size_t)b * NPTS * 3;
    for (int i = tid; i < NPTS; i += 256) {
        sx[i] = gp[3 * i + 0];
        sy[i] = gp[3 * i + 1];
        sz[i] = gp[3 * i + 2];
    }
    __syncthreads();

#define DECL(J) float x##J, y##J, z##J, d##J;
    X16(DECL)
#undef DECL
#define LOAD(J) { int li = (J)*256 + tid; x##J = sx[li]; y##J = sy[li]; z##J = sz[li]; d##J = 1e10f; }
    X16(LOAD)
#undef LOAD

    int   cur = 0;
    float qx = sx[0];
    float qy = sy[0];
    float qz = sz[0];

    for (int t = 0; t < KSEL; ++t) {
        if (tid == 0) sel[t] = cur;

        float bv = -1.0f;
        int   bi = 0x7fffffff;
        // exact reference arithmetic: (dx*dx + dy*dy) + dz*dz, no fma; fminf;
        // strict > keeps smallest index on ties (j ascending = idx ascending)
#define UPD(J) { \
        float dx = __fsub_rn(x##J, qx); \
        float dy = __fsub_rn(y##J, qy); \
        float dz = __fsub_rn(z##J, qz); \
        float dd = __fadd_rn(__fadd_rn(__fmul_rn(dx, dx), __fmul_rn(dy, dy)), \
                             __fmul_rn(dz, dz)); \
        d##J = fminf(d##J, dd); \
        if (d##J > bv) { bv = d##J; bi = (J)*256 + tid; } }
        X16(UPD)
#undef UPD

        // pack: nonneg float bits are order-preserving as unsigned;
        // tie -> larger ~idx -> smaller idx (matches argmax first-occurrence)
        unsigned long long p =
            (((unsigned long long)__float_as_uint(bv)) << 32) |
            (unsigned int)(~bi);
        unsigned long long porig = p;

        // speculative read of my own candidate's coords — conflict-free
        // (bank = tid&31), latency hides under the DPP chain below
        float wx = sx[bi];
        float wy = sy[bi];
        float wz = sz[bi];

        // DPP wave-64 max reduce into lane 63
        {
            unsigned int lo, hi, slo, shi;
#define DSTEP(CTRL) \
            lo = (unsigned int)p; hi = (unsigned int)(p >> 32); \
            slo = __builtin_amdgcn_update_dpp(0, (int)lo, CTRL, 0xf, 0xf, true); \
            shi = __builtin_amdgcn_update_dpp(0, (int)hi, CTRL, 0xf, 0xf, true); \
            p = dpp_max_step(p, slo, shi);
            DSTEP(0x111)  // row_shr:1
            DSTEP(0x112)  // row_shr:2
            DSTEP(0x114)  // row_shr:4
            DSTEP(0x118)  // row_shr:8
            DSTEP(0x142)  // row_bcast:15
            DSTEP(0x143)  // row_bcast:31
#undef DSTEP
        }

        // broadcast wave max from lane 63; unique winner lane (keys unique
        // by index) writes key + its candidate's coords to the wave slot
        unsigned int rlo = (unsigned int)__builtin_amdgcn_readlane((int)(unsigned int)p, 63);
        unsigned int rhi = (unsigned int)__builtin_amdgcn_readlane((int)(unsigned int)(p >> 32), 63);
        unsigned long long wavemax = (((unsigned long long)rhi) << 32) | rlo;

        int par = t & 1;
        if (porig == wavemax) {
            WSlot& s = wsl[par][tid >> 6];
            s.key = porig;
            s.x = wx;
            s.y = wy;
            s.z = wz;
        }
        __syncthreads();

        // single concurrent LDS round trip: 4x(key,xyz), broadcast reads
        unsigned long long k0 = wsl[par][0].key;
        float x0 = wsl[par][0].x, y0 = wsl[par][0].y, z0 = wsl[par][0].z;
        unsigned long long k1 = wsl[par][1].key;
        float x1 = wsl[par][1].x, y1 = wsl[par][1].y, z1 = wsl[par][1].z;
        unsigned long long k2 = wsl[par][2].key;
        float x2 = wsl[par][2].x, y2 = wsl[par][2].y, z2 = wsl[par][2].z;
        unsigned long long k3 = wsl[par][3].key;
        float x3 = wsl[par][3].x, y3 = wsl[par][3].y, z3 = wsl[par][3].z;

        bool b01 = k0 > k1;
        unsigned long long k01 = b01 ? k0 : k1;
        float x01 = b01 ? x0 : x1, y01 = b01 ? y0 : y1, z01 = b01 ? z0 : z1;
        bool b23 = k2 > k3;
        unsigned long long k23 = b23 ? k2 : k3;
        float x23 = b23 ? x2 : x3, y23 = b23 ? y2 : y3, z23 = b23 ? z2 : z3;
        bool bf = k01 > k23;
        unsigned long long kf = bf ? k01 : k23;
        qx = bf ? x01 : x23;
        qy = bf ? y01 : y23;
        qz = bf ? z01 : z23;
        cur = (int)(~(unsigned int)(kf & 0xffffffffULL));
    }
    __syncthreads();

    // epilogue: write selections in parallel, coalesced
    for (int t = tid; t < KSEL; t += 256) {
        int c = sel[t];
        int g = b * NPTS + c;
        int m = b * KSEL + t;
        fp_int[m] = g;
        inv[g] = m;
        out_fp[m] = (float)g;
        out_subx[m * 3 + 0] = sx[c];
        out_subx[m * 3 + 1] = sy[c];
        out_subx[m * 3 + 2] = sz[c];
    }
}

// ---------------- bucketed scatter (post-fps) ------------------------------
// Per-sampled-node fixed-capacity buckets (R4, measured good). cnt[m] doubles
// as the in-degree of sampled node m. Arrival order within a bucket is
// nondeterministic — tolerance covers it. CAP=80 overflow ~4e-13/node.
__global__ void scatter_kernel(const int* __restrict__ src, const int* __restrict__ dst,
                               const int* __restrict__ inv,
                               int* __restrict__ cnt, int* __restrict__ col2)
{
    int e = blockIdx.x * blockDim.x + threadIdx.x;
    if (e < N_EDGES) {
        int ld = inv[dst[e]];
        if (ld >= 0) {
            int slot = atomicAdd(&cnt[ld], 1);
            if (slot < CAP) col2[ld * CAP + slot] = src[e];
        }
    }
}

// ---------------- fused agg (blocks 0..2047) + edge (blocks 2048..4095) ---
__global__ void agg_edge_kernel(const float* __restrict__ feat,
                                const int* __restrict__ cnt,
                                const int* __restrict__ col2,
                                float* __restrict__ out_subfeat,
                                const int* __restrict__ src,
                                const int* __restrict__ dst,
                                const int* __restrict__ inv,
                                const float* __restrict__ subx,
                                float* __restrict__ outd,
                                float* __restrict__ outw,
                                float* __restrict__ outm)
{
    if (blockIdx.x < 2048) {
        // mean aggregation: one wave per sampled node; dual-edge float4
        // streams (lanes 0-31 even edges, 32-63 odd), Σ(even)+Σ(odd) —
        // association bit-identical to the proven two-stream unroll.
        int wid  = (blockIdx.x * blockDim.x + threadIdx.x) >> 6;
        int lane = threadIdx.x & 63;
        int half = lane >> 5;
        int l32  = lane & 31;
        int n = cnt[wid];          // exact in-degree of sampled node wid
        const int* cw = col2 + wid * CAP;
        float ax = 0.0f, ay = 0.0f, az = 0.0f, aw = 0.0f;
        int e = 0;
        for (; e + 1 < n; e += 2) {
            int sE = cw[e + half];
            float4 f = ((const float4*)(feat + (size_t)sE * D_FEAT))[l32];
            ax += f.x; ay += f.y; az += f.z; aw += f.w;
        }
        if (e < n && half == 0) {
            int sE = cw[e];
            float4 f = ((const float4*)(feat + (size_t)sE * D_FEAT))[l32];
            ax += f.x; ay += f.y; az += f.z; aw += f.w;
        }
        ax += __shfl_xor(ax, 32, 64);
        ay += __shfl_xor(ay, 32, 64);
        az += __shfl_xor(az, 32, 64);
        aw += __shfl_xor(aw, 32, 64);
        if (half == 0) {
            float dv = fmaxf((float)n, 1.0f);
            float4 o;
            o.x = ax / dv; o.y = ay / dv; o.z = az / dv; o.w = aw / dv;
            ((float4*)(out_subfeat + (size_t)wid * D_FEAT))[l32] = o;
        }
    } else {
        int e = (blockIdx.x - 2048) * blockDim.x + threadIdx.x;
        int ls = inv[src[e]];
        int ld = inv[dst[e]];
        bool mk = (ls >= 0) && (ld >= 0);
        float dx = 0.0f, dy = 0.0f, dz = 0.0f;
        if (mk) {
            dx = __fsub_rn(subx[ld * 3 + 0], subx[ls * 3 + 0]);
            dy = __fsub_rn(subx[ld * 3 + 1], subx[ls * 3 + 1]);
            dz = __fsub_rn(subx[ld * 3 + 2], subx[ls * 3 + 2]);
        }
        float w = sqrtf(__fadd_rn(__fadd_rn(__fmul_rn(dx, dx), __fmul_rn(dy, dy)),
                                  __fmul_rn(dz, dz)));
        outd[e * 3 + 0] = dx;
        outd[e * 3 + 1] = dy;
        outd[e * 3 + 2] = dz;
        outw[e] = w;
        outm[e] = mk ? 1.0f : 0.0f;
    }
}

// ---------------- launch ---------------------------------------------------
// Order: memset(cnt)=0, memset(inv)=0xFF (-1), fps, scatter, agg.
extern "C" void kernel_launch(void* const* d_in, const int* in_sizes, int n_in,
                              void* d_out, int out_size, void* d_ws, size_t ws_size,
                              hipStream_t stream)
{
    const float* pos  = (const float*)d_in[0];   // [16384,3]
    const float* feat = (const float*)d_in[1];   // [16384,128]
    const int*   src  = (const int*)d_in[2];     // [524288]
    const int*   dst  = (const int*)d_in[3];     // [524288]

    float* out = (float*)d_out;
    float* out_subx    = out;                                 // [8192,3]
    float* out_subfeat = out_subx + (size_t)MSEL * 3;         // [8192,128]
    float* out_d       = out_subfeat + (size_t)MSEL * D_FEAT; // [524288,3]
    float* out_w       = out_d + (size_t)N_EDGES * 3;         // [524288]
    float* out_m       = out_w + (size_t)N_EDGES;             // [524288]
    float* out_fp      = out_m + (size_t)N_EDGES;             // [8192]

    int* fp_int = (int*)d_ws;            // 8192
    int* inv    = fp_int + MSEL;         // 16384
    int* cnt    = inv + N_NODES;         // 8192
    int* col2   = cnt + MSEL;            // 8192*80 = 655360
    // total ws usage: (8192+16384+8192+655360)*4 = 2.75 MB

    (void)hipMemsetAsync(cnt, 0, (size_t)MSEL * 4, stream);
    (void)hipMemsetAsync(inv, 0xFF, (size_t)N_NODES * 4, stream);  // inv = -1

    fps_kernel<<<BATCH, 256, 0, stream>>>(pos, fp_int, inv, out_subx, out_fp);

    scatter_kernel<<<N_EDGES / 256, 256, 0, stream>>>(src, dst, inv, cnt, col2);

    agg_edge_kernel<<<4096, 256, 0, stream>>>(feat, cnt, col2,
                                              out_subfeat, src, dst, inv, out_subx,
                                              out_d, out_w, out_m);
}

// Round 6
// 1266.410 us; speedup vs baseline: 1.1573x; 1.1573x over previous
//
#include <hip/hip_runtime.h>
#include <math.h>

#define N_NODES 16384
#define N_EDGES 524288
#define D_FEAT  128
#define BATCH   4
#define NPTS    4096   // points per cloud
#define KSEL    2048   // selected per cloud
#define MSEL    (BATCH*KSEL)  // 8192
#define CAP     80     // per-sampled-node bucket capacity; deg~Poisson(32),
                       // P(deg>=80) ~ 4e-13/node -> safe; clamped anyway

#define X16(F) F(0) F(1) F(2) F(3) F(4) F(5) F(6) F(7) \
               F(8) F(9) F(10) F(11) F(12) F(13) F(14) F(15)

// ---------------------------------------------------------------------------
// FPS: R4 hot loop (measured 1107us) — THE measured optimum. Do not touch.
// R6 adds only: per-block init of inv/cnt slices at entry (replaces the two
// hipMemsetAsync dispatches; each block touches only its own cloud's slice,
// so no cross-block races; visibility to later kernels = stream order).
// Regression log (do not reintroduce without counter evidence):
//   winner-carried coords +248us (R5: readlane election on pre-barrier path,
//     16-load struct read + fat cndmask tree post-barrier);
//   512thr/2-waves-per-SIMD +127us (R2: barrier-lockstep kills wave overlap);
//   LDS atomicMax(u64) reduce +150us (R3: RMW on pre-barrier lgkmcnt path);
//   pk-asm packed math +100us; tournament-tree argmax +20-60us; two-phase
//   f32/u32 reduce +160us; float4-interleaved query +worse; fusing deg
//   blocks into this dispatch +60us AND races on inv.
// Conclusion after R2/R3/R5: fire-and-forget 4xb64 ds_write + redundant
// per-thread tree + broadcast query re-read is optimal; ~1107us is this
// structure's floor (serial 2048-iter chain, ~1296 cy/iter).
// ---------------------------------------------------------------------------

__device__ __forceinline__ unsigned long long dpp_max_step(unsigned long long p,
                                                           unsigned int slo,
                                                           unsigned int shi)
{
    unsigned long long s = (((unsigned long long)shi) << 32) | slo;
    return (s > p) ? s : p;
}

__launch_bounds__(256, 1)
__global__ void fps_kernel(const float* __restrict__ pos,
                           int* __restrict__ fp_int,
                           int* __restrict__ inv,
                           int* __restrict__ cnt,
                           float* __restrict__ out_subx,
                           float* __restrict__ out_fp)
{
    __shared__ float sx[NPTS];
    __shared__ float sy[NPTS];
    __shared__ float sz[NPTS];
    __shared__ int   sel[KSEL];
    __shared__ unsigned long long pwv[2][4];

    const int b   = blockIdx.x;
    const int tid = threadIdx.x;

    // init this cloud's inv slice (-1) and cnt slice (0) — replaces memsets
    for (int i = tid; i < NPTS; i += 256) inv[b * NPTS + i] = -1;
    for (int i = tid; i < KSEL; i += 256) cnt[b * KSEL + i] = 0;

    const float* gp = pos + (size_t)b * NPTS * 3;
    for (int i = tid; i < NPTS; i += 256) {
        sx[i] = gp[3 * i + 0];
        sy[i] = gp[3 * i + 1];
        sz[i] = gp[3 * i + 2];
    }
    __syncthreads();

#define DECL(J) float x##J, y##J, z##J, d##J;
    X16(DECL)
#undef DECL
#define LOAD(J) { int li = (J)*256 + tid; x##J = sx[li]; y##J = sy[li]; z##J = sz[li]; d##J = 1e10f; }
    X16(LOAD)
#undef LOAD

    int cur = 0;
    for (int t = 0; t < KSEL; ++t) {
        if (tid == 0) sel[t] = cur;
        float qx = sx[cur];
        float qy = sy[cur];
        float qz = sz[cur];

        float bv = -1.0f;
        int   bi = 0x7fffffff;
        // exact reference arithmetic: (dx*dx + dy*dy) + dz*dz, no fma; fminf;
        // strict > keeps smallest index on ties (j ascending = idx ascending)
#define UPD(J) { \
        float dx = __fsub_rn(x##J, qx); \
        float dy = __fsub_rn(y##J, qy); \
        float dz = __fsub_rn(z##J, qz); \
        float dd = __fadd_rn(__fadd_rn(__fmul_rn(dx, dx), __fmul_rn(dy, dy)), \
                             __fmul_rn(dz, dz)); \
        d##J = fminf(d##J, dd); \
        if (d##J > bv) { bv = d##J; bi = (J)*256 + tid; } }
        X16(UPD)
#undef UPD

        // pack: nonneg float bits are order-preserving as unsigned;
        // tie -> larger ~idx -> smaller idx (matches argmax first-occurrence)
        unsigned long long p =
            (((unsigned long long)__float_as_uint(bv)) << 32) |
            (unsigned int)(~bi);

        // DPP wave-64 max reduce into lane 63
        {
            unsigned int lo, hi, slo, shi;
#define DSTEP(CTRL) \
            lo = (unsigned int)p; hi = (unsigned int)(p >> 32); \
            slo = __builtin_amdgcn_update_dpp(0, (int)lo, CTRL, 0xf, 0xf, true); \
            shi = __builtin_amdgcn_update_dpp(0, (int)hi, CTRL, 0xf, 0xf, true); \
            p = dpp_max_step(p, slo, shi);
            DSTEP(0x111)  // row_shr:1
            DSTEP(0x112)  // row_shr:2
            DSTEP(0x114)  // row_shr:4
            DSTEP(0x118)  // row_shr:8
            DSTEP(0x142)  // row_bcast:15
            DSTEP(0x143)  // row_bcast:31
#undef DSTEP
        }

        int par = t & 1;
        if ((tid & 63) == 63) pwv[par][tid >> 6] = p;
        __syncthreads();

        unsigned long long c0 = pwv[par][0];
        unsigned long long c1 = pwv[par][1];
        unsigned long long c2 = pwv[par][2];
        unsigned long long c3 = pwv[par][3];
        unsigned long long m01 = (c0 > c1) ? c0 : c1;
        unsigned long long m23 = (c2 > c3) ? c2 : c3;
        unsigned long long mm  = (m01 > m23) ? m01 : m23;
        cur = (int)(~(unsigned int)(mm & 0xffffffffULL));
    }
    __syncthreads();

    // epilogue: write selections in parallel, coalesced
    for (int t = tid; t < KSEL; t += 256) {
        int c = sel[t];
        int g = b * NPTS + c;
        int m = b * KSEL + t;
        fp_int[m] = g;
        inv[g] = m;
        out_fp[m] = (float)g;
        out_subx[m * 3 + 0] = sx[c];
        out_subx[m * 3 + 1] = sy[c];
        out_subx[m * 3 + 2] = sz[c];
    }
}

// ---------------- fused scatter (blocks 0..2047) + edge out (2048..4095) ---
// Both halves depend only on fps (inv, subx) and are independent of each
// other: scatter is atomic/latency-bound, edge-half is write-BW-bound —
// co-residency overlaps them (R6). Bucketed scatter per R4: cnt[m] = exact
// in-degree of sampled node m; bucket order nondeterministic (tolerance
// covers it, constant absmax 0.001953 across rounds). CAP clamp = safety.
__global__ void scatter_edge_kernel(const int* __restrict__ src,
                                    const int* __restrict__ dst,
                                    const int* __restrict__ inv,
                                    int* __restrict__ cnt,
                                    int* __restrict__ col2,
                                    const float* __restrict__ subx,
                                    float* __restrict__ outd,
                                    float* __restrict__ outw,
                                    float* __restrict__ outm)
{
    if (blockIdx.x < 2048) {
        int e = blockIdx.x * blockDim.x + threadIdx.x;
        int ld = inv[dst[e]];
        if (ld >= 0) {
            int slot = atomicAdd(&cnt[ld], 1);
            if (slot < CAP) col2[ld * CAP + slot] = src[e];
        }
    } else {
        int e = (blockIdx.x - 2048) * blockDim.x + threadIdx.x;
        int ls = inv[src[e]];
        int ld = inv[dst[e]];
        bool mk = (ls >= 0) && (ld >= 0);
        float dx = 0.0f, dy = 0.0f, dz = 0.0f;
        if (mk) {
            dx = __fsub_rn(subx[ld * 3 + 0], subx[ls * 3 + 0]);
            dy = __fsub_rn(subx[ld * 3 + 1], subx[ls * 3 + 1]);
            dz = __fsub_rn(subx[ld * 3 + 2], subx[ls * 3 + 2]);
        }
        float w = sqrtf(__fadd_rn(__fadd_rn(__fmul_rn(dx, dx), __fmul_rn(dy, dy)),
                                  __fmul_rn(dz, dz)));
        outd[e * 3 + 0] = dx;
        outd[e * 3 + 1] = dy;
        outd[e * 3 + 2] = dz;
        outw[e] = w;
        outm[e] = mk ? 1.0f : 0.0f;
    }
}

// ---------------- mean aggregation (wave per sampled node) -----------------
// Dual-edge float4 streams (lanes 0-31 even edges, 32-63 odd), Σ(even)+Σ(odd)
// — association bit-identical to the proven two-stream unroll.
__global__ void agg_kernel(const float* __restrict__ feat,
                           const int* __restrict__ cnt,
                           const int* __restrict__ col2,
                           float* __restrict__ out_subfeat)
{
    int wid  = (blockIdx.x * blockDim.x + threadIdx.x) >> 6;
    int lane = threadIdx.x & 63;
    int half = lane >> 5;      // 0 = even-edge stream, 1 = odd-edge stream
    int l32  = lane & 31;      // column group: cols 4*l32 .. 4*l32+3
    int n = cnt[wid];          // exact in-degree of sampled node wid
    const int* cw = col2 + wid * CAP;
    float ax = 0.0f, ay = 0.0f, az = 0.0f, aw = 0.0f;
    int e = 0;
    for (; e + 1 < n; e += 2) {
        int sE = cw[e + half];
        float4 f = ((const float4*)(feat + (size_t)sE * D_FEAT))[l32];
        ax += f.x; ay += f.y; az += f.z; aw += f.w;
    }
    if (e < n && half == 0) {   // odd tail goes to the even stream (as before)
        int sE = cw[e];
        float4 f = ((const float4*)(feat + (size_t)sE * D_FEAT))[l32];
        ax += f.x; ay += f.y; az += f.z; aw += f.w;
    }
    // combine streams: lane l<32 holds A(cols 4l..), lane l+32 holds B(same)
    ax += __shfl_xor(ax, 32, 64);
    ay += __shfl_xor(ay, 32, 64);
    az += __shfl_xor(az, 32, 64);
    aw += __shfl_xor(aw, 32, 64);
    if (half == 0) {
        float dv = fmaxf((float)n, 1.0f);
        float4 o;
        o.x = ax / dv; o.y = ay / dv; o.z = az / dv; o.w = aw / dv;
        ((float4*)(out_subfeat + (size_t)wid * D_FEAT))[l32] = o;
    }
}

// ---------------- launch ---------------------------------------------------
// 3 dispatches: fps (inits inv/cnt itself), scatter_edge, agg.
// scatter_edge needs inv+subx (fps); agg needs cnt/col2 (scatter_edge).
extern "C" void kernel_launch(void* const* d_in, const int* in_sizes, int n_in,
                              void* d_out, int out_size, void* d_ws, size_t ws_size,
                              hipStream_t stream)
{
    const float* pos  = (const float*)d_in[0];   // [16384,3]
    const float* feat = (const float*)d_in[1];   // [16384,128]
    const int*   src  = (const int*)d_in[2];     // [524288]
    const int*   dst  = (const int*)d_in[3];     // [524288]

    float* out = (float*)d_out;
    float* out_subx    = out;                                 // [8192,3]
    float* out_subfeat = out_subx + (size_t)MSEL * 3;         // [8192,128]
    float* out_d       = out_subfeat + (size_t)MSEL * D_FEAT; // [524288,3]
    float* out_w       = out_d + (size_t)N_EDGES * 3;         // [524288]
    float* out_m       = out_w + (size_t)N_EDGES;             // [524288]
    float* out_fp      = out_m + (size_t)N_EDGES;             // [8192]

    int* fp_int = (int*)d_ws;            // 8192
    int* inv    = fp_int + MSEL;         // 16384
    int* cnt    = inv + N_NODES;         // 8192
    int* col2   = cnt + MSEL;            // 8192*80 = 655360
    // total ws usage: (8192+16384+8192+655360)*4 = 2.75 MB

    fps_kernel<<<BATCH, 256, 0, stream>>>(pos, fp_int, inv, cnt, out_subx, out_fp);

    scatter_edge_kernel<<<4096, 256, 0, stream>>>(src, dst, inv, cnt, col2,
                                                  out_subx, out_d, out_w, out_m);

    agg_kernel<<<2048, 256, 0, stream>>>(feat, cnt, col2, out_subfeat);
}

// Round 7
// 1216.849 us; speedup vs baseline: 1.2044x; 1.0407x over previous
//
#include <hip/hip_runtime.h>
#include <math.h>

#define N_NODES 16384
#define N_EDGES 524288
#define D_FEAT  128
#define BATCH   4
#define NPTS    4096   // points per cloud
#define KSEL    2048   // selected per cloud
#define MSEL    (BATCH*KSEL)  // 8192
#define CAP     80     // per-sampled-node bucket capacity; deg~Poisson(32),
                       // P(deg>=80) ~ 4e-13/node -> safe; clamped anyway

#define X16(F) F(0) F(1) F(2) F(3) F(4) F(5) F(6) F(7) \
               F(8) F(9) F(10) F(11) F(12) F(13) F(14) F(15)

// ---------------------------------------------------------------------------
// FPS: byte-identical to the measured-1107us R4 variant. DO NOT TOUCH —
// not even entry/exit code. R6 proved that adding mere init loops at entry
// perturbs the compiler's main-loop schedule (+51us, VALUBusy 0.985->0.94).
// Regression log (do not reintroduce without counter evidence):
//   entry-fused inv/cnt init +51us (R6: codegen perturbation of hot loop);
//   winner-carried coords +248us (R5: readlane election on pre-barrier path,
//     16-load struct read + fat cndmask tree post-barrier);
//   512thr/2-waves-per-SIMD +127us (R2: barrier-lockstep kills wave overlap);
//   LDS atomicMax(u64) reduce +150us (R3: RMW on pre-barrier lgkmcnt path);
//   pk-asm packed math +100us; tournament-tree argmax +20-60us; two-phase
//   f32/u32 reduce +160us; float4-interleaved query +worse; fusing deg
//   blocks into this dispatch +60us AND races on inv.
// Conclusion (7 variants): fire-and-forget 4xb64 ds_write + redundant
// per-thread tree + broadcast query re-read is optimal; ~1107us is this
// structure's floor (serial 2048-iter dependency chain, ~1296 cy/iter).
// inv is initialized by hipMemsetAsync(0xFF) BEFORE this kernel launches.
// ---------------------------------------------------------------------------

__device__ __forceinline__ unsigned long long dpp_max_step(unsigned long long p,
                                                           unsigned int slo,
                                                           unsigned int shi)
{
    unsigned long long s = (((unsigned long long)shi) << 32) | slo;
    return (s > p) ? s : p;
}

__launch_bounds__(256, 1)
__global__ void fps_kernel(const float* __restrict__ pos,
                           int* __restrict__ fp_int,
                           int* __restrict__ inv,
                           float* __restrict__ out_subx,
                           float* __restrict__ out_fp)
{
    __shared__ float sx[NPTS];
    __shared__ float sy[NPTS];
    __shared__ float sz[NPTS];
    __shared__ int   sel[KSEL];
    __shared__ unsigned long long pwv[2][4];

    const int b   = blockIdx.x;
    const int tid = threadIdx.x;

    const float* gp = pos + (size_t)b * NPTS * 3;
    for (int i = tid; i < NPTS; i += 256) {
        sx[i] = gp[3 * i + 0];
        sy[i] = gp[3 * i + 1];
        sz[i] = gp[3 * i + 2];
    }
    __syncthreads();

#define DECL(J) float x##J, y##J, z##J, d##J;
    X16(DECL)
#undef DECL
#define LOAD(J) { int li = (J)*256 + tid; x##J = sx[li]; y##J = sy[li]; z##J = sz[li]; d##J = 1e10f; }
    X16(LOAD)
#undef LOAD

    int cur = 0;
    for (int t = 0; t < KSEL; ++t) {
        if (tid == 0) sel[t] = cur;
        float qx = sx[cur];
        float qy = sy[cur];
        float qz = sz[cur];

        float bv = -1.0f;
        int   bi = 0x7fffffff;
        // exact reference arithmetic: (dx*dx + dy*dy) + dz*dz, no fma; fminf;
        // strict > keeps smallest index on ties (j ascending = idx ascending)
#define UPD(J) { \
        float dx = __fsub_rn(x##J, qx); \
        float dy = __fsub_rn(y##J, qy); \
        float dz = __fsub_rn(z##J, qz); \
        float dd = __fadd_rn(__fadd_rn(__fmul_rn(dx, dx), __fmul_rn(dy, dy)), \
                             __fmul_rn(dz, dz)); \
        d##J = fminf(d##J, dd); \
        if (d##J > bv) { bv = d##J; bi = (J)*256 + tid; } }
        X16(UPD)
#undef UPD

        // pack: nonneg float bits are order-preserving as unsigned;
        // tie -> larger ~idx -> smaller idx (matches argmax first-occurrence)
        unsigned long long p =
            (((unsigned long long)__float_as_uint(bv)) << 32) |
            (unsigned int)(~bi);

        // DPP wave-64 max reduce into lane 63
        {
            unsigned int lo, hi, slo, shi;
#define DSTEP(CTRL) \
            lo = (unsigned int)p; hi = (unsigned int)(p >> 32); \
            slo = __builtin_amdgcn_update_dpp(0, (int)lo, CTRL, 0xf, 0xf, true); \
            shi = __builtin_amdgcn_update_dpp(0, (int)hi, CTRL, 0xf, 0xf, true); \
            p = dpp_max_step(p, slo, shi);
            DSTEP(0x111)  // row_shr:1
            DSTEP(0x112)  // row_shr:2
            DSTEP(0x114)  // row_shr:4
            DSTEP(0x118)  // row_shr:8
            DSTEP(0x142)  // row_bcast:15
            DSTEP(0x143)  // row_bcast:31
#undef DSTEP
        }

        int par = t & 1;
        if ((tid & 63) == 63) pwv[par][tid >> 6] = p;
        __syncthreads();

        unsigned long long c0 = pwv[par][0];
        unsigned long long c1 = pwv[par][1];
        unsigned long long c2 = pwv[par][2];
        unsigned long long c3 = pwv[par][3];
        unsigned long long m01 = (c0 > c1) ? c0 : c1;
        unsigned long long m23 = (c2 > c3) ? c2 : c3;
        unsigned long long mm  = (m01 > m23) ? m01 : m23;
        cur = (int)(~(unsigned int)(mm & 0xffffffffULL));
    }
    __syncthreads();

    // epilogue: write selections in parallel, coalesced
    for (int t = tid; t < KSEL; t += 256) {
        int c = sel[t];
        int g = b * NPTS + c;
        int m = b * KSEL + t;
        fp_int[m] = g;
        inv[g] = m;
        out_fp[m] = (float)g;
        out_subx[m * 3 + 0] = sx[c];
        out_subx[m * 3 + 1] = sy[c];
        out_subx[m * 3 + 2] = sz[c];
    }
}

// ---------------- bucketed scatter (post-fps) ------------------------------
// Per-sampled-node fixed-capacity buckets (R4, measured good). cnt[m] doubles
// as the in-degree of sampled node m. Arrival order within a bucket is
// nondeterministic — tolerance covers it. CAP=80 overflow ~4e-13/node.
// R7: int2-vectorized — each thread handles 2 edges (one 8B dst load),
// halving address math and thread count. fps-independent change.
__global__ void scatter_kernel(const int* __restrict__ src, const int* __restrict__ dst,
                               const int* __restrict__ inv,
                               int* __restrict__ cnt, int* __restrict__ col2)
{
    int i = blockIdx.x * blockDim.x + threadIdx.x;   // edge pair index
    if (i < N_EDGES / 2) {
        int2 d2 = ((const int2*)dst)[i];
        int e0 = 2 * i;
        int ld0 = inv[d2.x];
        if (ld0 >= 0) {
            int slot = atomicAdd(&cnt[ld0], 1);
            if (slot < CAP) col2[ld0 * CAP + slot] = src[e0];
        }
        int ld1 = inv[d2.y];
        if (ld1 >= 0) {
            int slot = atomicAdd(&cnt[ld1], 1);
            if (slot < CAP) col2[ld1 * CAP + slot] = src[e0 + 1];
        }
    }
}

// ---------------- fused agg (blocks 0..2047) + edge (blocks 2048..4095) ---
__global__ void agg_edge_kernel(const float* __restrict__ feat,
                                const int* __restrict__ cnt,
                                const int* __restrict__ col2,
                                float* __restrict__ out_subfeat,
                                const int* __restrict__ src,
                                const int* __restrict__ dst,
                                const int* __restrict__ inv,
                                const float* __restrict__ subx,
                                float* __restrict__ outd,
                                float* __restrict__ outw,
                                float* __restrict__ outm)
{
    if (blockIdx.x < 2048) {
        // mean aggregation: one wave per sampled node; dual-edge float4
        // streams (lanes 0-31 even edges, 32-63 odd), Σ(even)+Σ(odd) —
        // association bit-identical to the proven two-stream unroll.
        int wid  = (blockIdx.x * blockDim.x + threadIdx.x) >> 6;
        int lane = threadIdx.x & 63;
        int half = lane >> 5;
        int l32  = lane & 31;
        int n = cnt[wid];          // exact in-degree of sampled node wid
        const int* cw = col2 + wid * CAP;
        float ax = 0.0f, ay = 0.0f, az = 0.0f, aw = 0.0f;
        int e = 0;
        for (; e + 1 < n; e += 2) {
            int sE = cw[e + half];
            float4 f = ((const float4*)(feat + (size_t)sE * D_FEAT))[l32];
            ax += f.x; ay += f.y; az += f.z; aw += f.w;
        }
        if (e < n && half == 0) {
            int sE = cw[e];
            float4 f = ((const float4*)(feat + (size_t)sE * D_FEAT))[l32];
            ax += f.x; ay += f.y; az += f.z; aw += f.w;
        }
        ax += __shfl_xor(ax, 32, 64);
        ay += __shfl_xor(ay, 32, 64);
        az += __shfl_xor(az, 32, 64);
        aw += __shfl_xor(aw, 32, 64);
        if (half == 0) {
            float dv = fmaxf((float)n, 1.0f);
            float4 o;
            o.x = ax / dv; o.y = ay / dv; o.z = az / dv; o.w = aw / dv;
            ((float4*)(out_subfeat + (size_t)wid * D_FEAT))[l32] = o;
        }
    } else {
        int e = (blockIdx.x - 2048) * blockDim.x + threadIdx.x;
        int ls = inv[src[e]];
        int ld = inv[dst[e]];
        bool mk = (ls >= 0) && (ld >= 0);
        float dx = 0.0f, dy = 0.0f, dz = 0.0f;
        if (mk) {
            dx = __fsub_rn(subx[ld * 3 + 0], subx[ls * 3 + 0]);
            dy = __fsub_rn(subx[ld * 3 + 1], subx[ls * 3 + 1]);
            dz = __fsub_rn(subx[ld * 3 + 2], subx[ls * 3 + 2]);
        }
        float w = sqrtf(__fadd_rn(__fadd_rn(__fmul_rn(dx, dx), __fmul_rn(dy, dy)),
                                  __fmul_rn(dz, dz)));
        outd[e * 3 + 0] = dx;
        outd[e * 3 + 1] = dy;
        outd[e * 3 + 2] = dz;
        outw[e] = w;
        outm[e] = mk ? 1.0f : 0.0f;
    }
}

// ---------------- launch ---------------------------------------------------
// Order: memset(cnt)=0, memset(inv)=0xFF (-1), fps, scatter, agg_edge.
// scatter needs inv (fps); agg needs cnt/col2 (scatter).
extern "C" void kernel_launch(void* const* d_in, const int* in_sizes, int n_in,
                              void* d_out, int out_size, void* d_ws, size_t ws_size,
                              hipStream_t stream)
{
    const float* pos  = (const float*)d_in[0];   // [16384,3]
    const float* feat = (const float*)d_in[1];   // [16384,128]
    const int*   src  = (const int*)d_in[2];     // [524288]
    const int*   dst  = (const int*)d_in[3];     // [524288]

    float* out = (float*)d_out;
    float* out_subx    = out;                                 // [8192,3]
    float* out_subfeat = out_subx + (size_t)MSEL * 3;         // [8192,128]
    float* out_d       = out_subfeat + (size_t)MSEL * D_FEAT; // [524288,3]
    float* out_w       = out_d + (size_t)N_EDGES * 3;         // [524288]
    float* out_m       = out_w + (size_t)N_EDGES;             // [524288]
    float* out_fp      = out_m + (size_t)N_EDGES;             // [8192]

    int* fp_int = (int*)d_ws;            // 8192
    int* inv    = fp_int + MSEL;         // 16384
    int* cnt    = inv + N_NODES;         // 8192
    int* col2   = cnt + MSEL;            // 8192*80 = 655360
    // total ws usage: (8192+16384+8192+655360)*4 = 2.75 MB

    (void)hipMemsetAsync(cnt, 0, (size_t)MSEL * 4, stream);
    (void)hipMemsetAsync(inv, 0xFF, (size_t)N_NODES * 4, stream);  // inv = -1

    fps_kernel<<<BATCH, 256, 0, stream>>>(pos, fp_int, inv, out_subx, out_fp);

    scatter_kernel<<<N_EDGES / 512, 256, 0, stream>>>(src, dst, inv, cnt, col2);

    agg_edge_kernel<<<4096, 256, 0, stream>>>(feat, cnt, col2,
                                              out_subfeat, src, dst, inv, out_subx,
                                              out_d, out_w, out_m);
}